// Round 9
// baseline (1929.209 us; speedup 1.0000x reference)
//
#include <hip/hip_runtime.h>
#include <hip/hip_bf16.h>

// Problem constants (from reference)
#define N_ATOMS 60000
#define N_BONDS 150000
#define MAX_NB 6
#define N_MOLS 2000
#define ATOM_FDIM 133
#define BOND_FDIM 14
#define HID 300
#define TAB 16

typedef __hip_bfloat16 bf16;
typedef __attribute__((ext_vector_type(8))) short short8;
typedef __attribute__((ext_vector_type(4))) float f32x4;

__device__ __forceinline__ float b2f(short s) {
  return __uint_as_float(((unsigned int)(unsigned short)s) << 16);
}
__device__ __forceinline__ short f2b(float f) {
  bf16 h = __float2bfloat16(f);
  return __builtin_bit_cast(short, h);
}

__device__ __forceinline__ float ldv(const float* __restrict__ p, size_t i) { return p[i]; }
__device__ __forceinline__ float ldv(const bf16* __restrict__ p, size_t i) { return __bfloat162float(p[i]); }
__device__ __forceinline__ void stv(float* __restrict__ p, size_t i, float v) { p[i] = v; }
__device__ __forceinline__ void stv(bf16* __restrict__ p, size_t i, float v) { p[i] = __float2bfloat16(v); }

// ============================================================================
// MFMA path: bf16 activations+weights, fp32 accum.
//   fa16 [60000][144], fb16 [150000][16], msgA/msgB [150000][320], nei [60000][320]
//   Wt[n][k] layouts as before (segment-padded transpose).
// AMODE 1 (init):  A[e] = [fa16[b2a[e]] | fb16[e]]
// AMODE 2 (atom):  A[a] = [fa16[a] | nei[a]]
// AMODE 3 (step, nm FUSED): A[e][k] = bf16(nei[b2a[e]][k] - msg[b2revb[e]][k])
// ============================================================================

template<int AMODE>
__device__ __forceinline__ short8 fetchA(int row, int kg,
                                         const bf16* __restrict__ src0,
                                         const bf16* __restrict__ src1,
                                         const int* __restrict__ gidx,
                                         const int* __restrict__ gidx2) {
  if constexpr (AMODE == 1) {
    if (kg < 18) {
      const int a = gidx[row];
      return *(const short8*)(src0 + (size_t)a * 144 + kg * 8);
    } else {
      return *(const short8*)(src1 + (size_t)row * 16 + (kg - 18) * 8);
    }
  } else if constexpr (AMODE == 2) {
    if (kg < 18) return *(const short8*)(src0 + (size_t)row * 144 + kg * 8);
    else if (kg < 58) return *(const short8*)(src1 + (size_t)row * 320 + (kg - 18) * 8);
    else { short8 z = {}; return z; }
  } else { // AMODE 3: fused nm = nei[b2a[e]] - msg[b2revb[e]], rounding identical to old nm16
    const int a = gidx[row];
    const int r = gidx2[row];
    short8 u = *(const short8*)(src0 + (size_t)a * 320 + kg * 8);
    short8 v = *(const short8*)(src1 + (size_t)r * 320 + kg * 8);
    short8 o;
    #pragma unroll
    for (int e = 0; e < 8; ++e) o[e] = f2b(b2f(u[e]) - b2f(v[e]));
    return o;
  }
}

// C = relu(A_virtual @ Wt^T (+bias)); tile 128x64, 4 waves (2x2), K-step 32.
template<int AMODE, typename TO, int KSTEPS>
__global__ __launch_bounds__(256)
void mfma_gemm(const bf16* __restrict__ src0, const bf16* __restrict__ src1,
               const int* __restrict__ gidx, const int* __restrict__ gidx2,
               const bf16* __restrict__ Wt,
               const float* __restrict__ bias, TO* __restrict__ C,
               int M, int Ncols, int ostride) {
  __shared__ __align__(16) short As[128 * 32];
  __shared__ __align__(16) short Bs[64 * 32];
  const int t = threadIdx.x;
  const int bm = blockIdx.x * 128;
  const int bn = blockIdx.y * 64;
  const int w = t >> 6, lane = t & 63;
  const int wr = w >> 1, wc = w & 1;
  const int lr = lane & 15, lk = lane >> 4;
  f32x4 acc[4][2] = {};
  for (int kt = 0; kt < KSTEPS; ++kt) {
    #pragma unroll
    for (int i = 0; i < 2; ++i) {
      const int s = t + 256 * i;
      const int row = s >> 2, kgl = s & 3;
      const int grow = bm + row;
      short8 v = {};
      if (grow < M) v = fetchA<AMODE>(grow, kt * 4 + kgl, src0, src1, gidx, gidx2);
      *(short8*)(As + row * 32 + ((kgl ^ (row & 3)) << 3)) = v;
    }
    {
      const int col = t >> 2, kgl = t & 3;
      short8 v = *(const short8*)(Wt + (size_t)(bn + col) * (KSTEPS * 32) + (size_t)(kt * 4 + kgl) * 8);
      *(short8*)(Bs + col * 32 + ((kgl ^ (col & 3)) << 3)) = v;
    }
    __syncthreads();
    short8 afr[4], bfr[2];
    #pragma unroll
    for (int m = 0; m < 4; ++m) {
      const int r = wr * 64 + m * 16 + lr;
      afr[m] = *(const short8*)(As + r * 32 + ((lk ^ (r & 3)) << 3));
    }
    #pragma unroll
    for (int n = 0; n < 2; ++n) {
      const int cc = wc * 32 + n * 16 + lr;
      bfr[n] = *(const short8*)(Bs + cc * 32 + ((lk ^ (cc & 3)) << 3));
    }
    #pragma unroll
    for (int m = 0; m < 4; ++m)
      #pragma unroll
      for (int n = 0; n < 2; ++n)
        acc[m][n] = __builtin_amdgcn_mfma_f32_16x16x32_bf16(afr[m], bfr[n], acc[m][n], 0, 0, 0);
    __syncthreads();
  }
  #pragma unroll
  for (int m = 0; m < 4; ++m) {
    #pragma unroll
    for (int n = 0; n < 2; ++n) {
      #pragma unroll
      for (int r = 0; r < 4; ++r) {
        const int row = bm + wr * 64 + m * 16 + lk * 4 + r;
        const int col = bn + wc * 32 + n * 16 + lr;
        if (row >= M) continue;
        if (col < Ncols) {
          float v = acc[m][n][r];
          if (bias) v += bias[col];
          stv(C, (size_t)row * ostride + col, fmaxf(v, 0.f));
        } else if (col < ostride) {
          stv(C, (size_t)row * ostride + col, 0.f);
        }
      }
    }
  }
}

__global__ __launch_bounds__(256)
void cvt_pad_kernel(const float* __restrict__ src, bf16* __restrict__ dst,
                    int rows, int scols, int dcols) {
  const int i = blockIdx.x * blockDim.x + threadIdx.x;
  if (i >= rows * dcols) return;
  const int r = i / dcols, c = i % dcols;
  dst[(size_t)r * dcols + c] = __float2bfloat16(c < scols ? src[(size_t)r * scols + c] : 0.f);
}

__global__ __launch_bounds__(256)
void wt_fill_kernel(const float* __restrict__ W, bf16* __restrict__ Wt,
                    int N, int Kp, int seg0_len, int seg1_dst, int seg1_src, int seg1_len) {
  const int i = blockIdx.x * blockDim.x + threadIdx.x;
  if (i >= 320 * Kp) return;
  const int n = i / Kp, kd = i % Kp;
  float v = 0.f;
  if (n < N) {
    if (kd < seg0_len) v = W[(size_t)kd * N + n];
    else if (kd >= seg1_dst && kd < seg1_dst + seg1_len)
      v = W[(size_t)(seg1_src + kd - seg1_dst) * N + n];
  }
  Wt[(size_t)n * Kp + kd] = __float2bfloat16(v);
}

__global__ __launch_bounds__(256)
void nei_sum16_kernel(const bf16* __restrict__ msg, const int* __restrict__ a2b,
                      bf16* __restrict__ nei) {
  const int i = blockIdx.x * blockDim.x + threadIdx.x;
  if (i >= N_ATOMS * 40) return;
  const int a = i / 40, c8 = (i % 40) * 8;
  const int* ab = a2b + (size_t)a * MAX_NB;
  float s[8] = {};
  #pragma unroll
  for (int j = 0; j < MAX_NB; ++j) {
    short8 v = *(const short8*)(msg + (size_t)ab[j] * 320 + c8);
    #pragma unroll
    for (int e = 0; e < 8; ++e) s[e] += b2f(v[e]);
  }
  short8 o;
  #pragma unroll
  for (int e = 0; e < 8; ++e) o[e] = f2b(s[e]);
  *(short8*)(nei + (size_t)a * 320 + c8) = o;
}

// ============================================================================
// Fused FFN + head: one block per mol. LDS-staged row; W reads coalesced.
// h = relu(comb@W1+b1); fp = relu(h@W2+b2); out = fp@hw + hb
// ============================================================================
__global__ __launch_bounds__(320)
void ffn_fused_kernel(const float* __restrict__ mv_il, const float* __restrict__ mv_hl,
                      const float* __restrict__ tab,
                      const float* __restrict__ w1, const float* __restrict__ b1,
                      const float* __restrict__ w2, const float* __restrict__ b2,
                      const float* __restrict__ hw, const float* __restrict__ hb,
                      float* __restrict__ out) {
  __shared__ float comb[616];
  __shared__ float h[300];
  __shared__ float fp[304];
  const int m = blockIdx.x;
  const int t = threadIdx.x;
  for (int k = t; k < 616; k += 320) {
    float v;
    if (k < 300) v = mv_il[(size_t)m * 300 + k];
    else if (k < 600) v = mv_hl[(size_t)m * 300 + (k - 300)];
    else v = tab[(size_t)m * TAB + (k - 600)];
    comb[k] = v;
  }
  __syncthreads();
  if (t < 300) {
    float a = 0.f;
    for (int k = 0; k < 616; ++k) a = fmaf(comb[k], w1[(size_t)k * 300 + t], a);
    h[t] = fmaxf(a + b1[t], 0.f);
  }
  __syncthreads();
  if (t < 300) {
    float a = 0.f;
    for (int k = 0; k < 300; ++k) a = fmaf(h[k], w2[(size_t)k * 300 + t], a);
    fp[t] = fmaxf(a + b2[t], 0.f) * hw[t];   // pre-scale by head weight
  }
  __syncthreads();
  if (t < 64) {
    float s = 0.f;
    for (int k = t; k < 300; k += 64) s += fp[k];
    #pragma unroll
    for (int off = 32; off; off >>= 1) s += __shfl_down(s, off, 64);
    if (t == 0) out[m] = s + hb[0];
  }
}

// ============================================================================
// Legacy fp32-FMA GEMM (fallback path only)
// ============================================================================
template<int MODE, typename TA>
__device__ __forceinline__ float loadA(int row, int k,
                                       const TA* __restrict__ A,
                                       const int* __restrict__ idx,
                                       const float* __restrict__ aux0,
                                       const TA* __restrict__ aux1,
                                       const float* __restrict__ aux2,
                                       int K) {
  if constexpr (MODE == 0) {
    return ldv(A, (size_t)row * K + k);
  } else if constexpr (MODE == 1) {
    return (k < ATOM_FDIM) ? aux0[(size_t)idx[row] * ATOM_FDIM + k]
                           : aux2[(size_t)row * BOND_FDIM + (k - ATOM_FDIM)];
  } else {
    return (k < ATOM_FDIM) ? aux0[(size_t)row * ATOM_FDIM + k]
                           : ldv(aux1, (size_t)row * HID + (k - ATOM_FDIM));
  }
}

constexpr int BM = 128, BN = 64, BK = 16;

template<int MODE, typename TA, typename TO>
__global__ __launch_bounds__(256)
void gemm_kernel(const TA* __restrict__ A, const int* __restrict__ idx,
                 const float* __restrict__ aux0, const TA* __restrict__ aux1,
                 const float* __restrict__ aux2,
                 const float* __restrict__ W, const float* __restrict__ bias,
                 TO* __restrict__ C, int M, int N, int K) {
  __shared__ float As[BK][BM + 4];
  __shared__ float Bs[BK][BN + 4];
  const int t = threadIdx.x;
  const int bm = blockIdx.x * BM;
  const int bn = blockIdx.y * BN;
  const int tx = t & 15;
  const int ty = t >> 4;
  float acc[8][4] = {};
  const int kTiles = (K + BK - 1) / BK;
  for (int kt = 0; kt < kTiles; ++kt) {
    const int k0 = kt * BK;
    {
      const int kk = t & 15;
      const int r0 = t >> 4;
      const int k = k0 + kk;
      #pragma unroll
      for (int i = 0; i < 8; ++i) {
        const int r = r0 + i * 16;
        const int row = bm + r;
        float v = 0.f;
        if (row < M && k < K) v = loadA<MODE, TA>(row, k, A, idx, aux0, aux1, aux2, K);
        As[kk][r] = v;
      }
    }
    {
      const int col = t & 63;
      const int kr = t >> 6;
      #pragma unroll
      for (int i = 0; i < 4; ++i) {
        const int k = k0 + kr + i * 4;
        float v = 0.f;
        if (k < K && (bn + col) < N) v = W[(size_t)k * N + bn + col];
        Bs[kr + i * 4][col] = v;
      }
    }
    __syncthreads();
    #pragma unroll
    for (int k = 0; k < BK; ++k) {
      float a[8], b[4];
      #pragma unroll
      for (int i = 0; i < 8; ++i) a[i] = As[k][ty * 8 + i];
      #pragma unroll
      for (int j = 0; j < 4; ++j) b[j] = Bs[k][tx * 4 + j];
      #pragma unroll
      for (int i = 0; i < 8; ++i)
        #pragma unroll
        for (int j = 0; j < 4; ++j)
          acc[i][j] = fmaf(a[i], b[j], acc[i][j]);
    }
    __syncthreads();
  }
  #pragma unroll
  for (int i = 0; i < 8; ++i) {
    const int row = bm + ty * 8 + i;
    if (row >= M) continue;
    #pragma unroll
    for (int j = 0; j < 4; ++j) {
      const int col = bn + tx * 4 + j;
      if (col >= N) continue;
      float v = acc[i][j];
      if (bias) v += bias[col];
      stv(C, (size_t)row * N + col, fmaxf(v, 0.f));
    }
  }
}

template<typename T>
__global__ __launch_bounds__(256)
void nei_sum_kernel(const T* __restrict__ msg, const int* __restrict__ a2b,
                    T* __restrict__ nei, int n_atoms) {
  const int i = blockIdx.x * blockDim.x + threadIdx.x;
  const int total = n_atoms * (HID / 4);
  if (i >= total) return;
  const int a = i / (HID / 4), c = (i % (HID / 4)) * 4;
  const int* ab = a2b + (size_t)a * MAX_NB;
  float s0 = 0.f, s1 = 0.f, s2 = 0.f, s3 = 0.f;
  #pragma unroll
  for (int j = 0; j < MAX_NB; ++j) {
    const size_t base = (size_t)ab[j] * HID + c;
    s0 += ldv(msg, base + 0); s1 += ldv(msg, base + 1);
    s2 += ldv(msg, base + 2); s3 += ldv(msg, base + 3);
  }
  const size_t ob = (size_t)a * HID + c;
  stv(nei, ob + 0, s0); stv(nei, ob + 1, s1);
  stv(nei, ob + 2, s2); stv(nei, ob + 3, s3);
}

template<typename T>
__global__ __launch_bounds__(256)
void nm_kernel(const T* __restrict__ nei, const T* __restrict__ msg,
               const int* __restrict__ b2a, const int* __restrict__ b2revb,
               T* __restrict__ nm, int n_bonds) {
  const int i = blockIdx.x * blockDim.x + threadIdx.x;
  const int total = n_bonds * (HID / 4);
  if (i >= total) return;
  const int e = i / (HID / 4), c = (i % (HID / 4)) * 4;
  const int a = b2a[e], r = b2revb[e];
  const size_t ub = (size_t)a * HID + c;
  const size_t vb = (size_t)r * HID + c;
  const size_t ob = (size_t)e * HID + c;
  stv(nm, ob + 0, ldv(nei, ub + 0) - ldv(msg, vb + 0));
  stv(nm, ob + 1, ldv(nei, ub + 1) - ldv(msg, vb + 1));
  stv(nm, ob + 2, ldv(nei, ub + 2) - ldv(msg, vb + 2));
  stv(nm, ob + 3, ldv(nei, ub + 3) - ldv(msg, vb + 3));
}

__device__ __forceinline__ int lower_bound_i(const int* __restrict__ arr, int n, int key) {
  int lo = 0, hi = n;
  while (lo < hi) { int mid = (lo + hi) >> 1; if (arr[mid] < key) lo = mid + 1; else hi = mid; }
  return lo;
}

__global__ __launch_bounds__(320)
void mol_mean_kernel(const float* __restrict__ atom_h, const int* __restrict__ mol_ids,
                     float* __restrict__ mv, int n_atoms) {
  const int m = blockIdx.x;
  const int start = lower_bound_i(mol_ids, n_atoms, m);
  const int end = lower_bound_i(mol_ids, n_atoms, m + 1);
  const int t = threadIdx.x;
  if (t < HID) {
    float s = 0.f;
    for (int a = start; a < end; ++a) s += atom_h[(size_t)a * HID + t];
    const float cnt = (float)(end - start);
    mv[(size_t)m * HID + t] = s / fmaxf(cnt, 1.0f);
  }
}

// legacy fallback encoder (bf16 storage, fp32 FMA GEMMs)
template<typename T>
static void run_encoder(const float* fa, const float* fb, const int* a2b,
                        const int* b2a, const int* b2revb, const int* mol_ids,
                        const float* W_i, const float* W_h,
                        const float* W_o_w, const float* W_o_b,
                        T* msgA, T* nmBuf, T* nei, float* atom_h, float* mv,
                        hipStream_t stream) {
  const dim3 blk(256);
  const dim3 gB((N_BONDS + BM - 1) / BM, (HID + BN - 1) / BN);
  const dim3 gA((N_ATOMS + BM - 1) / BM, (HID + BN - 1) / BN);
  const int neiBlocks = (N_ATOMS * (HID / 4) + 255) / 256;
  const int nmBlocks  = (N_BONDS * (HID / 4) + 255) / 256;

  gemm_kernel<1, T, T><<<gB, blk, 0, stream>>>((const T*)nullptr, b2a, fa, (const T*)nullptr, fb,
                                               W_i, nullptr, msgA,
                                               N_BONDS, HID, ATOM_FDIM + BOND_FDIM);
  for (int s = 0; s < 2; ++s) {
    nei_sum_kernel<T><<<neiBlocks, blk, 0, stream>>>(msgA, a2b, nei, N_ATOMS);
    nm_kernel<T><<<nmBlocks, blk, 0, stream>>>(nei, msgA, b2a, b2revb, nmBuf, N_BONDS);
    gemm_kernel<0, T, T><<<gB, blk, 0, stream>>>(nmBuf, nullptr, nullptr, (const T*)nullptr, nullptr,
                                                 W_h, nullptr, msgA,
                                                 N_BONDS, HID, HID);
  }
  nei_sum_kernel<T><<<neiBlocks, blk, 0, stream>>>(msgA, a2b, nei, N_ATOMS);
  gemm_kernel<2, T, float><<<gA, blk, 0, stream>>>((const T*)nullptr, nullptr, fa, nei, nullptr,
                                                   W_o_w, W_o_b, atom_h,
                                                   N_ATOMS, HID, ATOM_FDIM + HID);
  mol_mean_kernel<<<N_MOLS, 320, 0, stream>>>(atom_h, mol_ids, mv, N_ATOMS);
}

// ---------------- host ----------------
extern "C" void kernel_launch(void* const* d_in, const int* in_sizes, int n_in,
                              void* d_out, int out_size, void* d_ws, size_t ws_size,
                              hipStream_t stream) {
  const dim3 blk(256);

  // ---- MFMA-path workspace layout (bytes); keep same proven threshold ----
  const size_t msgBytes = (size_t)N_BONDS * 320 * 2;   // 96,000,000
  const size_t neiBytes = (size_t)N_ATOMS * 320 * 2;   // 38,400,000
  const size_t wtBytes  = (size_t)(320 * 160 + 320 * 320 + 320 * 480) * 2; // 614,400
  const size_t mvBytes  = (size_t)4 * N_MOLS * HID * 4; // 9,600,000
  const size_t needMFMA = 2 * msgBytes + neiBytes + wtBytes + mvBytes; // 240,614,400

  const size_t nMsg = (size_t)N_BONDS * HID;
  const size_t nNei = (size_t)N_ATOMS * HID;
  const size_t nMol = (size_t)N_MOLS * HID;
  const size_t needSmall = (2 * nMsg + nNei) * sizeof(bf16) + 4 * nMol * sizeof(float);

  const float* tab     = (const float*)d_in[20];
  const float* ffn_w1  = (const float*)d_in[21];
  const float* ffn_b1  = (const float*)d_in[22];
  const float* ffn_w2  = (const float*)d_in[23];
  const float* ffn_b2  = (const float*)d_in[24];
  const float* head_w  = (const float*)d_in[25];
  const float* head_b  = (const float*)d_in[26];

  float *mv_il, *mv_hl;

  if (ws_size >= needMFMA) {
    // ================= MFMA path =================
    char* base = (char*)d_ws;
    bf16* msgA = (bf16*)base;
    bf16* msgB = (bf16*)(base + msgBytes);
    bf16* nei  = (bf16*)(base + 2 * msgBytes);
    bf16* WiT  = (bf16*)(base + 2 * msgBytes + neiBytes);
    bf16* WhT  = WiT + 320 * 160;
    bf16* WoT  = WhT + 320 * 320;
    float* mvf = (float*)(base + 2 * msgBytes + neiBytes + wtBytes);
    mv_il = mvf; mv_hl = mvf + nMol;
    // fa16/fb16 overlay inside msgB (dead during init GEMM and atom GEMM)
    bf16* fa16 = msgB;
    bf16* fb16 = msgB + (size_t)N_ATOMS * 144;
    float* atom_h = (float*)msgA;  // overlay once msgA is dead (72MB < 96MB)

    const dim3 gB((N_BONDS + 127) / 128, 5);
    const dim3 gA((N_ATOMS + 127) / 128, 5);
    const int neiBlk = (N_ATOMS * 40 + 255) / 256;

    for (int c = 0; c < 2; ++c) {
      const float* fa      = (const float*)d_in[c * 10 + 0];
      const float* fb      = (const float*)d_in[c * 10 + 1];
      const int*   a2b     = (const int*)d_in[c * 10 + 2];
      const int*   b2a     = (const int*)d_in[c * 10 + 3];
      const int*   b2revb  = (const int*)d_in[c * 10 + 4];
      const int*   mol_ids = (const int*)d_in[c * 10 + 5];
      const float* W_i     = (const float*)d_in[c * 10 + 6];
      const float* W_h     = (const float*)d_in[c * 10 + 7];
      const float* W_o_w   = (const float*)d_in[c * 10 + 8];
      const float* W_o_b   = (const float*)d_in[c * 10 + 9];
      float* mv = (c == 0) ? mv_il : mv_hl;

      cvt_pad_kernel<<<(N_ATOMS * 144 + 255) / 256, blk, 0, stream>>>(fa, fa16, N_ATOMS, 133, 144);
      cvt_pad_kernel<<<(N_BONDS * 16 + 255) / 256, blk, 0, stream>>>(fb, fb16, N_BONDS, 14, 16);
      wt_fill_kernel<<<(320 * 160 + 255) / 256, blk, 0, stream>>>(W_i, WiT, 300, 160, 133, 144, 133, 14);
      wt_fill_kernel<<<(320 * 320 + 255) / 256, blk, 0, stream>>>(W_h, WhT, 300, 320, 300, 0, 0, 0);
      wt_fill_kernel<<<(320 * 480 + 255) / 256, blk, 0, stream>>>(W_o_w, WoT, 300, 480, 133, 144, 133, 300);

      // msg0 = relu([fa[b2a] | fb] @ W_i)  -> msgA
      mfma_gemm<1, bf16, 5><<<gB, blk, 0, stream>>>(fa16, fb16, b2a, nullptr, WiT, nullptr,
                                                    msgA, N_BONDS, 300, 320);
      // step 1: nei from msgA; fused-nm GEMM -> msgB
      nei_sum16_kernel<<<neiBlk, blk, 0, stream>>>(msgA, a2b, nei);
      mfma_gemm<3, bf16, 10><<<gB, blk, 0, stream>>>(nei, msgA, b2a, b2revb, WhT, nullptr,
                                                     msgB, N_BONDS, 300, 320);
      // step 2: nei from msgB; fused-nm GEMM -> msgA
      nei_sum16_kernel<<<neiBlk, blk, 0, stream>>>(msgB, a2b, nei);
      mfma_gemm<3, bf16, 10><<<gB, blk, 0, stream>>>(nei, msgB, b2a, b2revb, WhT, nullptr,
                                                     msgA, N_BONDS, 300, 320);
      // final gather; rebuild fa16 (msgB clobbered by step-1 output); atom GEMM
      nei_sum16_kernel<<<neiBlk, blk, 0, stream>>>(msgA, a2b, nei);
      cvt_pad_kernel<<<(N_ATOMS * 144 + 255) / 256, blk, 0, stream>>>(fa, fa16, N_ATOMS, 133, 144);
      mfma_gemm<2, float, 15><<<gA, blk, 0, stream>>>(fa16, nei, nullptr, nullptr, WoT, W_o_b,
                                                      atom_h, N_ATOMS, 300, 300);
      mol_mean_kernel<<<N_MOLS, 320, 0, stream>>>(atom_h, mol_ids, mv, N_ATOMS);
    }
  } else if (ws_size >= needSmall) {
    // ================= legacy bf16-FMA fallback =================
    bf16* p = (bf16*)d_ws;
    bf16* msgA_b = p;  p += nMsg;
    bf16* nm_b   = p;  p += nMsg;
    bf16* nei_b  = p;  p += nNei;
    float* q = (float*)p;
    mv_il = q; q += nMol;  mv_hl = q;
    float* atom_h = (float*)nm_b;

    for (int c = 0; c < 2; ++c) {
      const float* fa      = (const float*)d_in[c * 10 + 0];
      const float* fb      = (const float*)d_in[c * 10 + 1];
      const int*   a2b     = (const int*)d_in[c * 10 + 2];
      const int*   b2a     = (const int*)d_in[c * 10 + 3];
      const int*   b2revb  = (const int*)d_in[c * 10 + 4];
      const int*   mol_ids = (const int*)d_in[c * 10 + 5];
      const float* W_i     = (const float*)d_in[c * 10 + 6];
      const float* W_h     = (const float*)d_in[c * 10 + 7];
      const float* W_o_w   = (const float*)d_in[c * 10 + 8];
      const float* W_o_b   = (const float*)d_in[c * 10 + 9];
      float* mv = (c == 0) ? mv_il : mv_hl;
      run_encoder<bf16>(fa, fb, a2b, b2a, b2revb, mol_ids, W_i, W_h, W_o_w, W_o_b,
                        msgA_b, nm_b, nei_b, atom_h, mv, stream);
    }
  } else {
    hipMemsetAsync(d_out, 0, (size_t)out_size * sizeof(float), stream);
    return;
  }

  // ================= fused FFN + head =================
  ffn_fused_kernel<<<N_MOLS, 320, 0, stream>>>(mv_il, mv_hl, tab,
                                               ffn_w1, ffn_b1, ffn_w2, ffn_b2,
                                               head_w, head_b, (float*)d_out);
}

// Round 11
// 1529.872 us; speedup vs baseline: 1.2610x; 1.2610x over previous
//
#include <hip/hip_runtime.h>
#include <hip/hip_bf16.h>

// Problem constants (from reference)
#define N_ATOMS 60000
#define N_BONDS 150000
#define MAX_NB 6
#define N_MOLS 2000
#define ATOM_FDIM 133
#define BOND_FDIM 14
#define HID 300
#define TAB 16

typedef __hip_bfloat16 bf16;
typedef __attribute__((ext_vector_type(8))) short short8;
typedef __attribute__((ext_vector_type(4))) float f32x4;

__device__ __forceinline__ float b2f(short s) {
  return __uint_as_float(((unsigned int)(unsigned short)s) << 16);
}
__device__ __forceinline__ short f2b(float f) {
  bf16 h = __float2bfloat16(f);
  return __builtin_bit_cast(short, h);
}

__device__ __forceinline__ float ldv(const float* __restrict__ p, size_t i) { return p[i]; }
__device__ __forceinline__ float ldv(const bf16* __restrict__ p, size_t i) { return __bfloat162float(p[i]); }
__device__ __forceinline__ void stv(float* __restrict__ p, size_t i, float v) { p[i] = v; }
__device__ __forceinline__ void stv(bf16* __restrict__ p, size_t i, float v) { p[i] = __float2bfloat16(v); }

// ============================================================================
// MFMA path: bf16 activations+weights, fp32 accum. (round-8 proven structure)
//   fa16 [60000][144], fb16 [150000][16], msgA/msgB [150000][320], nei [60000][320]
// AMODE 0 (W_h step): A = nm buffer [row][320]  (LINEAR stream — gather done in nm16)
// AMODE 1 (init):     A[e] = [fa16[b2a[e]] | fb16[e]]
// AMODE 2 (atom out): A[a] = [fa16[a] | nei[a]]
// ============================================================================

template<int AMODE>
__device__ __forceinline__ short8 fetchA(int row, int kg,
                                         const bf16* __restrict__ src0,
                                         const bf16* __restrict__ src1,
                                         const int* __restrict__ gidx) {
  if constexpr (AMODE == 0) {
    return *(const short8*)(src0 + (size_t)row * 320 + kg * 8);
  } else if constexpr (AMODE == 1) {
    if (kg < 18) {
      const int a = gidx[row];
      return *(const short8*)(src0 + (size_t)a * 144 + kg * 8);
    } else {
      return *(const short8*)(src1 + (size_t)row * 16 + (kg - 18) * 8);
    }
  } else {
    if (kg < 18) return *(const short8*)(src0 + (size_t)row * 144 + kg * 8);
    else if (kg < 58) return *(const short8*)(src1 + (size_t)row * 320 + (kg - 18) * 8);
    else { short8 z = {}; return z; }
  }
}

// C = relu(A_virtual @ Wt^T (+bias)); tile 128x64, 4 waves (2x2), K-step 32.
template<int AMODE, typename TO, int KSTEPS>
__global__ __launch_bounds__(256)
void mfma_gemm(const bf16* __restrict__ src0, const bf16* __restrict__ src1,
               const int* __restrict__ gidx, const bf16* __restrict__ Wt,
               const float* __restrict__ bias, TO* __restrict__ C,
               int M, int Ncols, int ostride) {
  __shared__ __align__(16) short As[128 * 32];
  __shared__ __align__(16) short Bs[64 * 32];
  const int t = threadIdx.x;
  const int bm = blockIdx.x * 128;
  const int bn = blockIdx.y * 64;
  const int w = t >> 6, lane = t & 63;
  const int wr = w >> 1, wc = w & 1;
  const int lr = lane & 15, lk = lane >> 4;
  f32x4 acc[4][2] = {};
  for (int kt = 0; kt < KSTEPS; ++kt) {
    #pragma unroll
    for (int i = 0; i < 2; ++i) {
      const int s = t + 256 * i;
      const int row = s >> 2, kgl = s & 3;
      const int grow = bm + row;
      short8 v = {};
      if (grow < M) v = fetchA<AMODE>(grow, kt * 4 + kgl, src0, src1, gidx);
      *(short8*)(As + row * 32 + ((kgl ^ (row & 3)) << 3)) = v;
    }
    {
      const int col = t >> 2, kgl = t & 3;
      short8 v = *(const short8*)(Wt + (size_t)(bn + col) * (KSTEPS * 32) + (size_t)(kt * 4 + kgl) * 8);
      *(short8*)(Bs + col * 32 + ((kgl ^ (col & 3)) << 3)) = v;
    }
    __syncthreads();
    short8 afr[4], bfr[2];
    #pragma unroll
    for (int m = 0; m < 4; ++m) {
      const int r = wr * 64 + m * 16 + lr;
      afr[m] = *(const short8*)(As + r * 32 + ((lk ^ (r & 3)) << 3));
    }
    #pragma unroll
    for (int n = 0; n < 2; ++n) {
      const int cc = wc * 32 + n * 16 + lr;
      bfr[n] = *(const short8*)(Bs + cc * 32 + ((lk ^ (cc & 3)) << 3));
    }
    #pragma unroll
    for (int m = 0; m < 4; ++m)
      #pragma unroll
      for (int n = 0; n < 2; ++n)
        acc[m][n] = __builtin_amdgcn_mfma_f32_16x16x32_bf16(afr[m], bfr[n], acc[m][n], 0, 0, 0);
    __syncthreads();
  }
  #pragma unroll
  for (int m = 0; m < 4; ++m) {
    #pragma unroll
    for (int n = 0; n < 2; ++n) {
      #pragma unroll
      for (int r = 0; r < 4; ++r) {
        const int row = bm + wr * 64 + m * 16 + lk * 4 + r;
        const int col = bn + wc * 32 + n * 16 + lr;
        if (row >= M) continue;
        if (col < Ncols) {
          float v = acc[m][n][r];
          if (bias) v += bias[col];
          stv(C, (size_t)row * ostride + col, fmaxf(v, 0.f));
        } else if (col < ostride) {
          stv(C, (size_t)row * ostride + col, 0.f);
        }
      }
    }
  }
}

__global__ __launch_bounds__(256)
void cvt_pad_kernel(const float* __restrict__ src, bf16* __restrict__ dst,
                    int rows, int scols, int dcols) {
  const int i = blockIdx.x * blockDim.x + threadIdx.x;
  if (i >= rows * dcols) return;
  const int r = i / dcols, c = i % dcols;
  dst[(size_t)r * dcols + c] = __float2bfloat16(c < scols ? src[(size_t)r * scols + c] : 0.f);
}

__global__ __launch_bounds__(256)
void wt_fill_kernel(const float* __restrict__ W, bf16* __restrict__ Wt,
                    int N, int Kp, int seg0_len, int seg1_dst, int seg1_src, int seg1_len) {
  const int i = blockIdx.x * blockDim.x + threadIdx.x;
  if (i >= 320 * Kp) return;
  const int n = i / Kp, kd = i % Kp;
  float v = 0.f;
  if (n < N) {
    if (kd < seg0_len) v = W[(size_t)kd * N + n];
    else if (kd >= seg1_dst && kd < seg1_dst + seg1_len)
      v = W[(size_t)(seg1_src + kd - seg1_dst) * N + n];
  }
  Wt[(size_t)n * Kp + kd] = __float2bfloat16(v);
}

// nei[a][0:320] = sum_j msg[a2b[a][j]][0:320]  (full-row contiguous consumption)
__global__ __launch_bounds__(256)
void nei_sum16_kernel(const bf16* __restrict__ msg, const int* __restrict__ a2b,
                      bf16* __restrict__ nei) {
  const int i = blockIdx.x * blockDim.x + threadIdx.x;
  if (i >= N_ATOMS * 40) return;
  const int a = i / 40, c8 = (i % 40) * 8;
  const int* ab = a2b + (size_t)a * MAX_NB;
  float s[8] = {};
  #pragma unroll
  for (int j = 0; j < MAX_NB; ++j) {
    short8 v = *(const short8*)(msg + (size_t)ab[j] * 320 + c8);
    #pragma unroll
    for (int e = 0; e < 8; ++e) s[e] += b2f(v[e]);
  }
  short8 o;
  #pragma unroll
  for (int e = 0; e < 8; ++e) o[e] = f2b(s[e]);
  *(short8*)(nei + (size_t)a * 320 + c8) = o;
}

// nm[e] = nei[b2a[e]] - msg[b2revb[e]]  (full-row contiguous consumption)
__global__ __launch_bounds__(256)
void nm16_kernel(const bf16* __restrict__ nei, const bf16* __restrict__ msg,
                 const int* __restrict__ b2a, const int* __restrict__ b2revb,
                 bf16* __restrict__ nm) {
  const int i = blockIdx.x * blockDim.x + threadIdx.x;
  if (i >= N_BONDS * 40) return;
  const int e = i / 40, c8 = (i % 40) * 8;
  const int a = b2a[e], r = b2revb[e];
  short8 u = *(const short8*)(nei + (size_t)a * 320 + c8);
  short8 v = *(const short8*)(msg + (size_t)r * 320 + c8);
  short8 o;
  #pragma unroll
  for (int k = 0; k < 8; ++k) o[k] = f2b(b2f(u[k]) - b2f(v[k]));
  *(short8*)(nm + (size_t)e * 320 + c8) = o;
}

// ============================================================================
// Fused FFN + head: one block per mol (2000 blocks vs 80 for the old GEMM path).
// ============================================================================
__global__ __launch_bounds__(320)
void ffn_fused_kernel(const float* __restrict__ mv_il, const float* __restrict__ mv_hl,
                      const float* __restrict__ tab,
                      const float* __restrict__ w1, const float* __restrict__ b1,
                      const float* __restrict__ w2, const float* __restrict__ b2,
                      const float* __restrict__ hw, const float* __restrict__ hb,
                      float* __restrict__ out) {
  __shared__ float comb[616];
  __shared__ float h[300];
  __shared__ float fp[304];
  const int m = blockIdx.x;
  const int t = threadIdx.x;
  for (int k = t; k < 616; k += 320) {
    float v;
    if (k < 300) v = mv_il[(size_t)m * 300 + k];
    else if (k < 600) v = mv_hl[(size_t)m * 300 + (k - 300)];
    else v = tab[(size_t)m * TAB + (k - 600)];
    comb[k] = v;
  }
  __syncthreads();
  if (t < 300) {
    float a = 0.f;
    for (int k = 0; k < 616; ++k) a = fmaf(comb[k], w1[(size_t)k * 300 + t], a);
    h[t] = fmaxf(a + b1[t], 0.f);
  }
  __syncthreads();
  if (t < 300) {
    float a = 0.f;
    for (int k = 0; k < 300; ++k) a = fmaf(h[k], w2[(size_t)k * 300 + t], a);
    fp[t] = fmaxf(a + b2[t], 0.f) * hw[t];   // pre-scale by head weight
  }
  __syncthreads();
  if (t < 64) {
    float s = 0.f;
    for (int k = t; k < 300; k += 64) s += fp[k];
    #pragma unroll
    for (int off = 32; off; off >>= 1) s += __shfl_down(s, off, 64);
    if (t == 0) out[m] = s + hb[0];
  }
}

// ============================================================================
// Legacy fp32-FMA GEMM (fallback path only)
// ============================================================================
template<int MODE, typename TA>
__device__ __forceinline__ float loadA(int row, int k,
                                       const TA* __restrict__ A,
                                       const int* __restrict__ idx,
                                       const float* __restrict__ aux0,
                                       const TA* __restrict__ aux1,
                                       const float* __restrict__ aux2,
                                       int K) {
  if constexpr (MODE == 0) {
    return ldv(A, (size_t)row * K + k);
  } else if constexpr (MODE == 1) {
    return (k < ATOM_FDIM) ? aux0[(size_t)idx[row] * ATOM_FDIM + k]
                           : aux2[(size_t)row * BOND_FDIM + (k - ATOM_FDIM)];
  } else {
    return (k < ATOM_FDIM) ? aux0[(size_t)row * ATOM_FDIM + k]
                           : ldv(aux1, (size_t)row * HID + (k - ATOM_FDIM));
  }
}

constexpr int BM = 128, BN = 64, BK = 16;

template<int MODE, typename TA, typename TO>
__global__ __launch_bounds__(256)
void gemm_kernel(const TA* __restrict__ A, const int* __restrict__ idx,
                 const float* __restrict__ aux0, const TA* __restrict__ aux1,
                 const float* __restrict__ aux2,
                 const float* __restrict__ W, const float* __restrict__ bias,
                 TO* __restrict__ C, int M, int N, int K) {
  __shared__ float As[BK][BM + 4];
  __shared__ float Bs[BK][BN + 4];
  const int t = threadIdx.x;
  const int bm = blockIdx.x * BM;
  const int bn = blockIdx.y * BN;
  const int tx = t & 15;
  const int ty = t >> 4;
  float acc[8][4] = {};
  const int kTiles = (K + BK - 1) / BK;
  for (int kt = 0; kt < kTiles; ++kt) {
    const int k0 = kt * BK;
    {
      const int kk = t & 15;
      const int r0 = t >> 4;
      const int k = k0 + kk;
      #pragma unroll
      for (int i = 0; i < 8; ++i) {
        const int r = r0 + i * 16;
        const int row = bm + r;
        float v = 0.f;
        if (row < M && k < K) v = loadA<MODE, TA>(row, k, A, idx, aux0, aux1, aux2, K);
        As[kk][r] = v;
      }
    }
    {
      const int col = t & 63;
      const int kr = t >> 6;
      #pragma unroll
      for (int i = 0; i < 4; ++i) {
        const int k = k0 + kr + i * 4;
        float v = 0.f;
        if (k < K && (bn + col) < N) v = W[(size_t)k * N + bn + col];
        Bs[kr + i * 4][col] = v;
      }
    }
    __syncthreads();
    #pragma unroll
    for (int k = 0; k < BK; ++k) {
      float a[8], b[4];
      #pragma unroll
      for (int i = 0; i < 8; ++i) a[i] = As[k][ty * 8 + i];
      #pragma unroll
      for (int j = 0; j < 4; ++j) b[j] = Bs[k][tx * 4 + j];
      #pragma unroll
      for (int i = 0; i < 8; ++i)
        #pragma unroll
        for (int j = 0; j < 4; ++j)
          acc[i][j] = fmaf(a[i], b[j], acc[i][j]);
    }
    __syncthreads();
  }
  #pragma unroll
  for (int i = 0; i < 8; ++i) {
    const int row = bm + ty * 8 + i;
    if (row >= M) continue;
    #pragma unroll
    for (int j = 0; j < 4; ++j) {
      const int col = bn + tx * 4 + j;
      if (col >= N) continue;
      float v = acc[i][j];
      if (bias) v += bias[col];
      stv(C, (size_t)row * N + col, fmaxf(v, 0.f));
    }
  }
}

template<typename T>
__global__ __launch_bounds__(256)
void nei_sum_kernel(const T* __restrict__ msg, const int* __restrict__ a2b,
                    T* __restrict__ nei, int n_atoms) {
  const int i = blockIdx.x * blockDim.x + threadIdx.x;
  const int total = n_atoms * (HID / 4);
  if (i >= total) return;
  const int a = i / (HID / 4), c = (i % (HID / 4)) * 4;
  const int* ab = a2b + (size_t)a * MAX_NB;
  float s0 = 0.f, s1 = 0.f, s2 = 0.f, s3 = 0.f;
  #pragma unroll
  for (int j = 0; j < MAX_NB; ++j) {
    const size_t base = (size_t)ab[j] * HID + c;
    s0 += ldv(msg, base + 0); s1 += ldv(msg, base + 1);
    s2 += ldv(msg, base + 2); s3 += ldv(msg, base + 3);
  }
  const size_t ob = (size_t)a * HID + c;
  stv(nei, ob + 0, s0); stv(nei, ob + 1, s1);
  stv(nei, ob + 2, s2); stv(nei, ob + 3, s3);
}

template<typename T>
__global__ __launch_bounds__(256)
void nm_kernel(const T* __restrict__ nei, const T* __restrict__ msg,
               const int* __restrict__ b2a, const int* __restrict__ b2revb,
               T* __restrict__ nm, int n_bonds) {
  const int i = blockIdx.x * blockDim.x + threadIdx.x;
  const int total = n_bonds * (HID / 4);
  if (i >= total) return;
  const int e = i / (HID / 4), c = (i % (HID / 4)) * 4;
  const int a = b2a[e], r = b2revb[e];
  const size_t ub = (size_t)a * HID + c;
  const size_t vb = (size_t)r * HID + c;
  const size_t ob = (size_t)e * HID + c;
  stv(nm, ob + 0, ldv(nei, ub + 0) - ldv(msg, vb + 0));
  stv(nm, ob + 1, ldv(nei, ub + 1) - ldv(msg, vb + 1));
  stv(nm, ob + 2, ldv(nei, ub + 2) - ldv(msg, vb + 2));
  stv(nm, ob + 3, ldv(nei, ub + 3) - ldv(msg, vb + 3));
}

__device__ __forceinline__ int lower_bound_i(const int* __restrict__ arr, int n, int key) {
  int lo = 0, hi = n;
  while (lo < hi) { int mid = (lo + hi) >> 1; if (arr[mid] < key) lo = mid + 1; else hi = mid; }
  return lo;
}

__global__ __launch_bounds__(320)
void mol_mean_kernel(const float* __restrict__ atom_h, const int* __restrict__ mol_ids,
                     float* __restrict__ mv, int n_atoms) {
  const int m = blockIdx.x;
  const int start = lower_bound_i(mol_ids, n_atoms, m);
  const int end = lower_bound_i(mol_ids, n_atoms, m + 1);
  const int t = threadIdx.x;
  if (t < HID) {
    float s = 0.f;
    for (int a = start; a < end; ++a) s += atom_h[(size_t)a * HID + t];
    const float cnt = (float)(end - start);
    mv[(size_t)m * HID + t] = s / fmaxf(cnt, 1.0f);
  }
}

// legacy fallback encoder (bf16 storage, fp32 FMA GEMMs)
template<typename T>
static void run_encoder(const float* fa, const float* fb, const int* a2b,
                        const int* b2a, const int* b2revb, const int* mol_ids,
                        const float* W_i, const float* W_h,
                        const float* W_o_w, const float* W_o_b,
                        T* msgA, T* nmBuf, T* nei, float* atom_h, float* mv,
                        hipStream_t stream) {
  const dim3 blk(256);
  const dim3 gB((N_BONDS + BM - 1) / BM, (HID + BN - 1) / BN);
  const dim3 gA((N_ATOMS + BM - 1) / BM, (HID + BN - 1) / BN);
  const int neiBlocks = (N_ATOMS * (HID / 4) + 255) / 256;
  const int nmBlocks  = (N_BONDS * (HID / 4) + 255) / 256;

  gemm_kernel<1, T, T><<<gB, blk, 0, stream>>>((const T*)nullptr, b2a, fa, (const T*)nullptr, fb,
                                               W_i, nullptr, msgA,
                                               N_BONDS, HID, ATOM_FDIM + BOND_FDIM);
  for (int s = 0; s < 2; ++s) {
    nei_sum_kernel<T><<<neiBlocks, blk, 0, stream>>>(msgA, a2b, nei, N_ATOMS);
    nm_kernel<T><<<nmBlocks, blk, 0, stream>>>(nei, msgA, b2a, b2revb, nmBuf, N_BONDS);
    gemm_kernel<0, T, T><<<gB, blk, 0, stream>>>(nmBuf, nullptr, nullptr, (const T*)nullptr, nullptr,
                                                 W_h, nullptr, msgA,
                                                 N_BONDS, HID, HID);
  }
  nei_sum_kernel<T><<<neiBlocks, blk, 0, stream>>>(msgA, a2b, nei, N_ATOMS);
  gemm_kernel<2, T, float><<<gA, blk, 0, stream>>>((const T*)nullptr, nullptr, fa, nei, nullptr,
                                                   W_o_w, W_o_b, atom_h,
                                                   N_ATOMS, HID, ATOM_FDIM + HID);
  mol_mean_kernel<<<N_MOLS, 320, 0, stream>>>(atom_h, mol_ids, mv, N_ATOMS);
}

// ---------------- host ----------------
extern "C" void kernel_launch(void* const* d_in, const int* in_sizes, int n_in,
                              void* d_out, int out_size, void* d_ws, size_t ws_size,
                              hipStream_t stream) {
  const dim3 blk(256);

  // ---- MFMA-path workspace layout (bytes); same proven threshold ----
  const size_t msgBytes = (size_t)N_BONDS * 320 * 2;   // 96,000,000
  const size_t neiBytes = (size_t)N_ATOMS * 320 * 2;   // 38,400,000
  const size_t wtBytes  = (size_t)(320 * 160 + 320 * 320 + 320 * 480) * 2; // 614,400
  const size_t mvBytes  = (size_t)4 * N_MOLS * HID * 4; // 9,600,000
  const size_t needMFMA = 2 * msgBytes + neiBytes + wtBytes + mvBytes; // 240,614,400

  const size_t nMsg = (size_t)N_BONDS * HID;
  const size_t nNei = (size_t)N_ATOMS * HID;
  const size_t nMol = (size_t)N_MOLS * HID;
  const size_t needSmall = (2 * nMsg + nNei) * sizeof(bf16) + 4 * nMol * sizeof(float);

  const float* tab     = (const float*)d_in[20];
  const float* ffn_w1  = (const float*)d_in[21];
  const float* ffn_b1  = (const float*)d_in[22];
  const float* ffn_w2  = (const float*)d_in[23];
  const float* ffn_b2  = (const float*)d_in[24];
  const float* head_w  = (const float*)d_in[25];
  const float* head_b  = (const float*)d_in[26];

  float *mv_il, *mv_hl;

  if (ws_size >= needMFMA) {
    // ================= MFMA path (round-8 structure) =================
    char* base = (char*)d_ws;
    bf16* msgA = (bf16*)base;
    bf16* msgB = (bf16*)(base + msgBytes);
    bf16* nei  = (bf16*)(base + 2 * msgBytes);
    bf16* WiT  = (bf16*)(base + 2 * msgBytes + neiBytes);
    bf16* WhT  = WiT + 320 * 160;
    bf16* WoT  = WhT + 320 * 320;
    float* mvf = (float*)(base + 2 * msgBytes + neiBytes + wtBytes);
    mv_il = mvf; mv_hl = mvf + nMol;
    // fa16/fb16 overlay inside msgB (dead during init GEMM)
    bf16* fa16 = msgB;
    bf16* fb16 = msgB + (size_t)N_ATOMS * 144;
    float* atom_h = (float*)msgA;  // overlay once msgA is dead (72MB < 96MB)

    const dim3 gB((N_BONDS + 127) / 128, 5);
    const dim3 gA((N_ATOMS + 127) / 128, 5);
    const int neiBlk = (N_ATOMS * 40 + 255) / 256;
    const int nmBlk  = (N_BONDS * 40 + 255) / 256;

    for (int c = 0; c < 2; ++c) {
      const float* fa      = (const float*)d_in[c * 10 + 0];
      const float* fb      = (const float*)d_in[c * 10 + 1];
      const int*   a2b     = (const int*)d_in[c * 10 + 2];
      const int*   b2a     = (const int*)d_in[c * 10 + 3];
      const int*   b2revb  = (const int*)d_in[c * 10 + 4];
      const int*   mol_ids = (const int*)d_in[c * 10 + 5];
      const float* W_i     = (const float*)d_in[c * 10 + 6];
      const float* W_h     = (const float*)d_in[c * 10 + 7];
      const float* W_o_w   = (const float*)d_in[c * 10 + 8];
      const float* W_o_b   = (const float*)d_in[c * 10 + 9];
      float* mv = (c == 0) ? mv_il : mv_hl;

      cvt_pad_kernel<<<(N_ATOMS * 144 + 255) / 256, blk, 0, stream>>>(fa, fa16, N_ATOMS, 133, 144);
      cvt_pad_kernel<<<(N_BONDS * 16 + 255) / 256, blk, 0, stream>>>(fb, fb16, N_BONDS, 14, 16);
      wt_fill_kernel<<<(320 * 160 + 255) / 256, blk, 0, stream>>>(W_i, WiT, 300, 160, 133, 144, 133, 14);
      wt_fill_kernel<<<(320 * 320 + 255) / 256, blk, 0, stream>>>(W_h, WhT, 300, 320, 300, 0, 0, 0);
      wt_fill_kernel<<<(320 * 480 + 255) / 256, blk, 0, stream>>>(W_o_w, WoT, 300, 480, 133, 144, 133, 300);

      // msg0 = relu([fa[b2a] | fb] @ W_i)
      mfma_gemm<1, bf16, 5><<<gB, blk, 0, stream>>>(fa16, fb16, b2a, WiT, nullptr,
                                                    msgA, N_BONDS, 300, 320);
      // 2 message-passing steps: gather kernels full-row, GEMM A linear
      for (int s = 0; s < 2; ++s) {
        nei_sum16_kernel<<<neiBlk, blk, 0, stream>>>(msgA, a2b, nei);
        nm16_kernel<<<nmBlk, blk, 0, stream>>>(nei, msgA, b2a, b2revb, msgB);
        mfma_gemm<0, bf16, 10><<<gB, blk, 0, stream>>>(msgB, nullptr, nullptr, WhT, nullptr,
                                                       msgA, N_BONDS, 300, 320);
      }
      // rebuild fa16 (msgB clobbered by nm), final gather, atom GEMM
      cvt_pad_kernel<<<(N_ATOMS * 144 + 255) / 256, blk, 0, stream>>>(fa, fa16, N_ATOMS, 133, 144);
      nei_sum16_kernel<<<neiBlk, blk, 0, stream>>>(msgA, a2b, nei);
      mfma_gemm<2, float, 15><<<gA, blk, 0, stream>>>(fa16, nei, nullptr, WoT, W_o_b,
                                                      atom_h, N_ATOMS, 300, 300);
      mol_mean_kernel<<<N_MOLS, 320, 0, stream>>>(atom_h, mol_ids, mv, N_ATOMS);
    }
  } else if (ws_size >= needSmall) {
    // ================= legacy bf16-FMA fallback =================
    bf16* p = (bf16*)d_ws;
    bf16* msgA_b = p;  p += nMsg;
    bf16* nm_b   = p;  p += nMsg;
    bf16* nei_b  = p;  p += nNei;
    float* q = (float*)p;
    mv_il = q; q += nMol;  mv_hl = q;
    float* atom_h = (float*)nm_b;

    for (int c = 0; c < 2; ++c) {
      const float* fa      = (const float*)d_in[c * 10 + 0];
      const float* fb      = (const float*)d_in[c * 10 + 1];
      const int*   a2b     = (const int*)d_in[c * 10 + 2];
      const int*   b2a     = (const int*)d_in[c * 10 + 3];
      const int*   b2revb  = (const int*)d_in[c * 10 + 4];
      const int*   mol_ids = (const int*)d_in[c * 10 + 5];
      const float* W_i     = (const float*)d_in[c * 10 + 6];
      const float* W_h     = (const float*)d_in[c * 10 + 7];
      const float* W_o_w   = (const float*)d_in[c * 10 + 8];
      const float* W_o_b   = (const float*)d_in[c * 10 + 9];
      float* mv = (c == 0) ? mv_il : mv_hl;
      run_encoder<bf16>(fa, fb, a2b, b2a, b2revb, mol_ids, W_i, W_h, W_o_w, W_o_b,
                        msgA_b, nm_b, nei_b, atom_h, mv, stream);
    }
  } else {
    hipMemsetAsync(d_out, 0, (size_t)out_size * sizeof(float), stream);
    return;
  }

  // ================= fused FFN + head =================
  ffn_fused_kernel<<<N_MOLS, 320, 0, stream>>>(mv_il, mv_hl, tab,
                                               ffn_w1, ffn_b1, ffn_w2, ffn_b2,
                                               head_w, head_b, (float*)d_out);
}

// Round 12
// 1470.968 us; speedup vs baseline: 1.3115x; 1.0400x over previous
//
#include <hip/hip_runtime.h>
#include <hip/hip_bf16.h>

// Problem constants (from reference)
#define N_ATOMS 60000
#define N_BONDS 150000
#define MAX_NB 6
#define N_MOLS 2000
#define ATOM_FDIM 133
#define BOND_FDIM 14
#define HID 300
#define TAB 16

typedef __hip_bfloat16 bf16;
typedef __attribute__((ext_vector_type(8))) short short8;
typedef __attribute__((ext_vector_type(4))) float f32x4;

__device__ __forceinline__ float b2f(short s) {
  return __uint_as_float(((unsigned int)(unsigned short)s) << 16);
}
__device__ __forceinline__ short f2b(float f) {
  bf16 h = __float2bfloat16(f);
  return __builtin_bit_cast(short, h);
}

__device__ __forceinline__ float ldv(const float* __restrict__ p, size_t i) { return p[i]; }
__device__ __forceinline__ float ldv(const bf16* __restrict__ p, size_t i) { return __bfloat162float(p[i]); }
__device__ __forceinline__ void stv(float* __restrict__ p, size_t i, float v) { p[i] = v; }
__device__ __forceinline__ void stv(bf16* __restrict__ p, size_t i, float v) { p[i] = __float2bfloat16(v); }

// async global->LDS, 16B per lane; LDS dest = wave-uniform base + lane*16
__device__ __forceinline__ void gld_lds16(const void* g, void* l) {
  __builtin_amdgcn_global_load_lds(
      (const __attribute__((address_space(1))) unsigned int*)g,
      (__attribute__((address_space(3))) unsigned int*)l, 16, 0, 0);
}

// ============================================================================
// MFMA path: bf16 activations+weights, fp32 accum.
//   fa16 [60000][144], fb16 [150000][16], msgA/msgB [150000][320], nei [60000][320]
// AMODE 0 (W_h step): A = nm buffer [row][320] (linear rows) — GLD staging
// AMODE 1 (init):     A[e] = [fa16[b2a[e]] | fb16[e]]        — GLD staging (per-lane src)
// AMODE 2 (atom out): A[a] = [fa16[a] | nei[a]] + zero tail  — register staging
// LDS layout: linear slots (row,kglslot), 16B each; XOR swizzle folded into the
// SOURCE k-offset on the write side; read side uses byte = row*64+((lk^(row&3))*16).
// ============================================================================

template<int AMODE>
__device__ __forceinline__ short8 fetchA_reg(int row, int kg,
                                             const bf16* __restrict__ src0,
                                             const bf16* __restrict__ src1) {
  // AMODE 2 only
  if (kg < 18) return *(const short8*)(src0 + (size_t)row * 144 + kg * 8);
  else if (kg < 58) return *(const short8*)(src1 + (size_t)row * 320 + (kg - 18) * 8);
  else { short8 z = {}; return z; }
}

// C = relu(A_virtual @ Wt^T (+bias)); tile 128x64, 4 waves (2x2), K-step 32.
template<int AMODE, typename TO, int KSTEPS>
__global__ __launch_bounds__(256)
void mfma_gemm(const bf16* __restrict__ src0, const bf16* __restrict__ src1,
               const int* __restrict__ gidx, const bf16* __restrict__ Wt,
               const float* __restrict__ bias, TO* __restrict__ C,
               int M, int Ncols, int ostride) {
  __shared__ __align__(16) short As[128 * 32];
  __shared__ __align__(16) short Bs[64 * 32];
  const int t = threadIdx.x;
  const int bm = blockIdx.x * 128;
  const int bn = blockIdx.y * 64;
  const int w = t >> 6, lane = t & 63;
  const int wr = w >> 1, wc = w & 1;
  const int lr = lane & 15, lk = lane >> 4;
  f32x4 acc[4][2] = {};
  for (int kt = 0; kt < KSTEPS; ++kt) {
    if constexpr (AMODE != 2) {
      // A stage via global_load_lds: 512 slots, 2 per thread, linear LDS dest
      #pragma unroll
      for (int i = 0; i < 2; ++i) {
        const int slot0 = 256 * i + 64 * w;       // wave-uniform LDS base slot
        const int slot = slot0 + lane;
        const int row = slot >> 2, kgl = slot & 3;
        const int grow = min(bm + row, M - 1);    // clamp: tail outputs discarded
        const int kg = kt * 4 + (kgl ^ (row & 3)); // swizzle folded into source
        const bf16* src;
        if constexpr (AMODE == 0) {
          src = src0 + (size_t)grow * 320 + kg * 8;
        } else {
          src = (kg < 18) ? (src0 + (size_t)gidx[grow] * 144 + kg * 8)
                          : (src1 + (size_t)grow * 16 + (kg - 18) * 8);
        }
        gld_lds16(src, (char*)As + slot0 * 16);
      }
    } else {
      #pragma unroll
      for (int i = 0; i < 2; ++i) {
        const int s = t + 256 * i;
        const int row = s >> 2, kgl = s & 3;
        const int grow = bm + row;
        short8 v = {};
        if (grow < M) v = fetchA_reg<AMODE>(grow, kt * 4 + kgl, src0, src1);
        *(short8*)(As + row * 32 + ((kgl ^ (row & 3)) << 3)) = v;
      }
    }
    { // B stage via global_load_lds: 256 slots, 1 per thread
      const int slot0 = 64 * w;
      const int slot = slot0 + lane;
      const int col = slot >> 2, kgl = slot & 3;
      const int kk = kt * 32 + ((kgl ^ (col & 3)) * 8);
      const bf16* src = Wt + (size_t)(bn + col) * (KSTEPS * 32) + kk;
      gld_lds16(src, (char*)Bs + slot0 * 16);
    }
    __syncthreads();
    short8 afr[4], bfr[2];
    #pragma unroll
    for (int m = 0; m < 4; ++m) {
      const int r = wr * 64 + m * 16 + lr;
      afr[m] = *(const short8*)(As + r * 32 + ((lk ^ (r & 3)) << 3));
    }
    #pragma unroll
    for (int n = 0; n < 2; ++n) {
      const int cc = wc * 32 + n * 16 + lr;
      bfr[n] = *(const short8*)(Bs + cc * 32 + ((lk ^ (cc & 3)) << 3));
    }
    #pragma unroll
    for (int m = 0; m < 4; ++m)
      #pragma unroll
      for (int n = 0; n < 2; ++n)
        acc[m][n] = __builtin_amdgcn_mfma_f32_16x16x32_bf16(afr[m], bfr[n], acc[m][n], 0, 0, 0);
    __syncthreads();
  }
  #pragma unroll
  for (int m = 0; m < 4; ++m) {
    #pragma unroll
    for (int n = 0; n < 2; ++n) {
      #pragma unroll
      for (int r = 0; r < 4; ++r) {
        const int row = bm + wr * 64 + m * 16 + lk * 4 + r;
        const int col = bn + wc * 32 + n * 16 + lr;
        if (row >= M) continue;
        if (col < Ncols) {
          float v = acc[m][n][r];
          if (bias) v += bias[col];
          stv(C, (size_t)row * ostride + col, fmaxf(v, 0.f));
        } else if (col < ostride) {
          stv(C, (size_t)row * ostride + col, 0.f);
        }
      }
    }
  }
}

__global__ __launch_bounds__(256)
void cvt_pad_kernel(const float* __restrict__ src, bf16* __restrict__ dst,
                    int rows, int scols, int dcols) {
  const int i = blockIdx.x * blockDim.x + threadIdx.x;
  if (i >= rows * dcols) return;
  const int r = i / dcols, c = i % dcols;
  dst[(size_t)r * dcols + c] = __float2bfloat16(c < scols ? src[(size_t)r * scols + c] : 0.f);
}

__global__ __launch_bounds__(256)
void wt_fill_kernel(const float* __restrict__ W, bf16* __restrict__ Wt,
                    int N, int Kp, int seg0_len, int seg1_dst, int seg1_src, int seg1_len) {
  const int i = blockIdx.x * blockDim.x + threadIdx.x;
  if (i >= 320 * Kp) return;
  const int n = i / Kp, kd = i % Kp;
  float v = 0.f;
  if (n < N) {
    if (kd < seg0_len) v = W[(size_t)kd * N + n];
    else if (kd >= seg1_dst && kd < seg1_dst + seg1_len)
      v = W[(size_t)(seg1_src + kd - seg1_dst) * N + n];
  }
  Wt[(size_t)n * Kp + kd] = __float2bfloat16(v);
}

// nei[a][0:320] = sum_j msg[a2b[a][j]][0:320]
__global__ __launch_bounds__(256)
void nei_sum16_kernel(const bf16* __restrict__ msg, const int* __restrict__ a2b,
                      bf16* __restrict__ nei) {
  const int i = blockIdx.x * blockDim.x + threadIdx.x;
  if (i >= N_ATOMS * 40) return;
  const int a = i / 40, c8 = (i % 40) * 8;
  const int* ab = a2b + (size_t)a * MAX_NB;
  float s[8] = {};
  #pragma unroll
  for (int j = 0; j < MAX_NB; ++j) {
    short8 v = *(const short8*)(msg + (size_t)ab[j] * 320 + c8);
    #pragma unroll
    for (int e = 0; e < 8; ++e) s[e] += b2f(v[e]);
  }
  short8 o;
  #pragma unroll
  for (int e = 0; e < 8; ++e) o[e] = f2b(s[e]);
  *(short8*)(nei + (size_t)a * 320 + c8) = o;
}

// nm[e] = nei[b2a[e]] - msg[b2revb[e]]
__global__ __launch_bounds__(256)
void nm16_kernel(const bf16* __restrict__ nei, const bf16* __restrict__ msg,
                 const int* __restrict__ b2a, const int* __restrict__ b2revb,
                 bf16* __restrict__ nm) {
  const int i = blockIdx.x * blockDim.x + threadIdx.x;
  if (i >= N_BONDS * 40) return;
  const int e = i / 40, c8 = (i % 40) * 8;
  const int a = b2a[e], r = b2revb[e];
  short8 u = *(const short8*)(nei + (size_t)a * 320 + c8);
  short8 v = *(const short8*)(msg + (size_t)r * 320 + c8);
  short8 o;
  #pragma unroll
  for (int k = 0; k < 8; ++k) o[k] = f2b(b2f(u[k]) - b2f(v[k]));
  *(short8*)(nm + (size_t)e * 320 + c8) = o;
}

// ============================================================================
// Fused FFN + head: one block per mol; unroll-4 with 4 accumulators (ILP).
// ============================================================================
__global__ __launch_bounds__(320)
void ffn_fused_kernel(const float* __restrict__ mv_il, const float* __restrict__ mv_hl,
                      const float* __restrict__ tab,
                      const float* __restrict__ w1, const float* __restrict__ b1,
                      const float* __restrict__ w2, const float* __restrict__ b2,
                      const float* __restrict__ hw, const float* __restrict__ hb,
                      float* __restrict__ out) {
  __shared__ float comb[616];
  __shared__ float h[300];
  __shared__ float fp[304];
  const int m = blockIdx.x;
  const int t = threadIdx.x;
  for (int k = t; k < 616; k += 320) {
    float v;
    if (k < 300) v = mv_il[(size_t)m * 300 + k];
    else if (k < 600) v = mv_hl[(size_t)m * 300 + (k - 300)];
    else v = tab[(size_t)m * TAB + (k - 600)];
    comb[k] = v;
  }
  __syncthreads();
  if (t < 300) {
    float a0 = 0.f, a1 = 0.f, a2 = 0.f, a3 = 0.f;
    #pragma unroll 4
    for (int k = 0; k < 616; k += 4) {   // 616 = 4*154
      a0 = fmaf(comb[k + 0], w1[(size_t)(k + 0) * 300 + t], a0);
      a1 = fmaf(comb[k + 1], w1[(size_t)(k + 1) * 300 + t], a1);
      a2 = fmaf(comb[k + 2], w1[(size_t)(k + 2) * 300 + t], a2);
      a3 = fmaf(comb[k + 3], w1[(size_t)(k + 3) * 300 + t], a3);
    }
    h[t] = fmaxf(((a0 + a1) + (a2 + a3)) + b1[t], 0.f);
  }
  __syncthreads();
  if (t < 300) {
    float a0 = 0.f, a1 = 0.f, a2 = 0.f, a3 = 0.f;
    #pragma unroll 4
    for (int k = 0; k < 300; k += 4) {   // 300 = 4*75
      a0 = fmaf(h[k + 0], w2[(size_t)(k + 0) * 300 + t], a0);
      a1 = fmaf(h[k + 1], w2[(size_t)(k + 1) * 300 + t], a1);
      a2 = fmaf(h[k + 2], w2[(size_t)(k + 2) * 300 + t], a2);
      a3 = fmaf(h[k + 3], w2[(size_t)(k + 3) * 300 + t], a3);
    }
    fp[t] = fmaxf(((a0 + a1) + (a2 + a3)) + b2[t], 0.f) * hw[t];  // pre-scale by head w
  }
  __syncthreads();
  if (t < 64) {
    float s = 0.f;
    for (int k = t; k < 300; k += 64) s += fp[k];
    #pragma unroll
    for (int off = 32; off; off >>= 1) s += __shfl_down(s, off, 64);
    if (t == 0) out[m] = s + hb[0];
  }
}

// ============================================================================
// Legacy fp32-FMA GEMM (fallback path only)
// ============================================================================
template<int MODE, typename TA>
__device__ __forceinline__ float loadA(int row, int k,
                                       const TA* __restrict__ A,
                                       const int* __restrict__ idx,
                                       const float* __restrict__ aux0,
                                       const TA* __restrict__ aux1,
                                       const float* __restrict__ aux2,
                                       int K) {
  if constexpr (MODE == 0) {
    return ldv(A, (size_t)row * K + k);
  } else if constexpr (MODE == 1) {
    return (k < ATOM_FDIM) ? aux0[(size_t)idx[row] * ATOM_FDIM + k]
                           : aux2[(size_t)row * BOND_FDIM + (k - ATOM_FDIM)];
  } else {
    return (k < ATOM_FDIM) ? aux0[(size_t)row * ATOM_FDIM + k]
                           : ldv(aux1, (size_t)row * HID + (k - ATOM_FDIM));
  }
}

constexpr int BM = 128, BN = 64, BK = 16;

template<int MODE, typename TA, typename TO>
__global__ __launch_bounds__(256)
void gemm_kernel(const TA* __restrict__ A, const int* __restrict__ idx,
                 const float* __restrict__ aux0, const TA* __restrict__ aux1,
                 const float* __restrict__ aux2,
                 const float* __restrict__ W, const float* __restrict__ bias,
                 TO* __restrict__ C, int M, int N, int K) {
  __shared__ float As[BK][BM + 4];
  __shared__ float Bs[BK][BN + 4];
  const int t = threadIdx.x;
  const int bm = blockIdx.x * BM;
  const int bn = blockIdx.y * BN;
  const int tx = t & 15;
  const int ty = t >> 4;
  float acc[8][4] = {};
  const int kTiles = (K + BK - 1) / BK;
  for (int kt = 0; kt < kTiles; ++kt) {
    const int k0 = kt * BK;
    {
      const int kk = t & 15;
      const int r0 = t >> 4;
      const int k = k0 + kk;
      #pragma unroll
      for (int i = 0; i < 8; ++i) {
        const int r = r0 + i * 16;
        const int row = bm + r;
        float v = 0.f;
        if (row < M && k < K) v = loadA<MODE, TA>(row, k, A, idx, aux0, aux1, aux2, K);
        As[kk][r] = v;
      }
    }
    {
      const int col = t & 63;
      const int kr = t >> 6;
      #pragma unroll
      for (int i = 0; i < 4; ++i) {
        const int k = k0 + kr + i * 4;
        float v = 0.f;
        if (k < K && (bn + col) < N) v = W[(size_t)k * N + bn + col];
        Bs[kr + i * 4][col] = v;
      }
    }
    __syncthreads();
    #pragma unroll
    for (int k = 0; k < BK; ++k) {
      float a[8], b[4];
      #pragma unroll
      for (int i = 0; i < 8; ++i) a[i] = As[k][ty * 8 + i];
      #pragma unroll
      for (int j = 0; j < 4; ++j) b[j] = Bs[k][tx * 4 + j];
      #pragma unroll
      for (int i = 0; i < 8; ++i)
        #pragma unroll
        for (int j = 0; j < 4; ++j)
          acc[i][j] = fmaf(a[i], b[j], acc[i][j]);
    }
    __syncthreads();
  }
  #pragma unroll
  for (int i = 0; i < 8; ++i) {
    const int row = bm + ty * 8 + i;
    if (row >= M) continue;
    #pragma unroll
    for (int j = 0; j < 4; ++j) {
      const int col = bn + tx * 4 + j;
      if (col >= N) continue;
      float v = acc[i][j];
      if (bias) v += bias[col];
      stv(C, (size_t)row * N + col, fmaxf(v, 0.f));
    }
  }
}

template<typename T>
__global__ __launch_bounds__(256)
void nei_sum_kernel(const T* __restrict__ msg, const int* __restrict__ a2b,
                    T* __restrict__ nei, int n_atoms) {
  const int i = blockIdx.x * blockDim.x + threadIdx.x;
  const int total = n_atoms * (HID / 4);
  if (i >= total) return;
  const int a = i / (HID / 4), c = (i % (HID / 4)) * 4;
  const int* ab = a2b + (size_t)a * MAX_NB;
  float s0 = 0.f, s1 = 0.f, s2 = 0.f, s3 = 0.f;
  #pragma unroll
  for (int j = 0; j < MAX_NB; ++j) {
    const size_t base = (size_t)ab[j] * HID + c;
    s0 += ldv(msg, base + 0); s1 += ldv(msg, base + 1);
    s2 += ldv(msg, base + 2); s3 += ldv(msg, base + 3);
  }
  const size_t ob = (size_t)a * HID + c;
  stv(nei, ob + 0, s0); stv(nei, ob + 1, s1);
  stv(nei, ob + 2, s2); stv(nei, ob + 3, s3);
}

template<typename T>
__global__ __launch_bounds__(256)
void nm_kernel(const T* __restrict__ nei, const T* __restrict__ msg,
               const int* __restrict__ b2a, const int* __restrict__ b2revb,
               T* __restrict__ nm, int n_bonds) {
  const int i = blockIdx.x * blockDim.x + threadIdx.x;
  const int total = n_bonds * (HID / 4);
  if (i >= total) return;
  const int e = i / (HID / 4), c = (i % (HID / 4)) * 4;
  const int a = b2a[e], r = b2revb[e];
  const size_t ub = (size_t)a * HID + c;
  const size_t vb = (size_t)r * HID + c;
  const size_t ob = (size_t)e * HID + c;
  stv(nm, ob + 0, ldv(nei, ub + 0) - ldv(msg, vb + 0));
  stv(nm, ob + 1, ldv(nei, ub + 1) - ldv(msg, vb + 1));
  stv(nm, ob + 2, ldv(nei, ub + 2) - ldv(msg, vb + 2));
  stv(nm, ob + 3, ldv(nei, ub + 3) - ldv(msg, vb + 3));
}

__device__ __forceinline__ int lower_bound_i(const int* __restrict__ arr, int n, int key) {
  int lo = 0, hi = n;
  while (lo < hi) { int mid = (lo + hi) >> 1; if (arr[mid] < key) lo = mid + 1; else hi = mid; }
  return lo;
}

__global__ __launch_bounds__(320)
void mol_mean_kernel(const float* __restrict__ atom_h, const int* __restrict__ mol_ids,
                     float* __restrict__ mv, int n_atoms) {
  const int m = blockIdx.x;
  const int start = lower_bound_i(mol_ids, n_atoms, m);
  const int end = lower_bound_i(mol_ids, n_atoms, m + 1);
  const int t = threadIdx.x;
  if (t < HID) {
    float s = 0.f;
    for (int a = start; a < end; ++a) s += atom_h[(size_t)a * HID + t];
    const float cnt = (float)(end - start);
    mv[(size_t)m * HID + t] = s / fmaxf(cnt, 1.0f);
  }
}

// legacy fallback encoder (bf16 storage, fp32 FMA GEMMs)
template<typename T>
static void run_encoder(const float* fa, const float* fb, const int* a2b,
                        const int* b2a, const int* b2revb, const int* mol_ids,
                        const float* W_i, const float* W_h,
                        const float* W_o_w, const float* W_o_b,
                        T* msgA, T* nmBuf, T* nei, float* atom_h, float* mv,
                        hipStream_t stream) {
  const dim3 blk(256);
  const dim3 gB((N_BONDS + BM - 1) / BM, (HID + BN - 1) / BN);
  const dim3 gA((N_ATOMS + BM - 1) / BM, (HID + BN - 1) / BN);
  const int neiBlocks = (N_ATOMS * (HID / 4) + 255) / 256;
  const int nmBlocks  = (N_BONDS * (HID / 4) + 255) / 256;

  gemm_kernel<1, T, T><<<gB, blk, 0, stream>>>((const T*)nullptr, b2a, fa, (const T*)nullptr, fb,
                                               W_i, nullptr, msgA,
                                               N_BONDS, HID, ATOM_FDIM + BOND_FDIM);
  for (int s = 0; s < 2; ++s) {
    nei_sum_kernel<T><<<neiBlocks, blk, 0, stream>>>(msgA, a2b, nei, N_ATOMS);
    nm_kernel<T><<<nmBlocks, blk, 0, stream>>>(nei, msgA, b2a, b2revb, nmBuf, N_BONDS);
    gemm_kernel<0, T, T><<<gB, blk, 0, stream>>>(nmBuf, nullptr, nullptr, (const T*)nullptr, nullptr,
                                                 W_h, nullptr, msgA,
                                                 N_BONDS, HID, HID);
  }
  nei_sum_kernel<T><<<neiBlocks, blk, 0, stream>>>(msgA, a2b, nei, N_ATOMS);
  gemm_kernel<2, T, float><<<gA, blk, 0, stream>>>((const T*)nullptr, nullptr, fa, nei, nullptr,
                                                   W_o_w, W_o_b, atom_h,
                                                   N_ATOMS, HID, ATOM_FDIM + HID);
  mol_mean_kernel<<<N_MOLS, 320, 0, stream>>>(atom_h, mol_ids, mv, N_ATOMS);
}

// ---------------- host ----------------
extern "C" void kernel_launch(void* const* d_in, const int* in_sizes, int n_in,
                              void* d_out, int out_size, void* d_ws, size_t ws_size,
                              hipStream_t stream) {
  const dim3 blk(256);

  // ---- MFMA-path workspace layout (bytes); same proven threshold ----
  const size_t msgBytes = (size_t)N_BONDS * 320 * 2;   // 96,000,000
  const size_t neiBytes = (size_t)N_ATOMS * 320 * 2;   // 38,400,000
  const size_t wtBytes  = (size_t)(320 * 160 + 320 * 320 + 320 * 480) * 2; // 614,400
  const size_t mvBytes  = (size_t)4 * N_MOLS * HID * 4; // 9,600,000
  const size_t needMFMA = 2 * msgBytes + neiBytes + wtBytes + mvBytes; // 240,614,400

  const size_t nMsg = (size_t)N_BONDS * HID;
  const size_t nNei = (size_t)N_ATOMS * HID;
  const size_t nMol = (size_t)N_MOLS * HID;
  const size_t needSmall = (2 * nMsg + nNei) * sizeof(bf16) + 4 * nMol * sizeof(float);

  const float* tab     = (const float*)d_in[20];
  const float* ffn_w1  = (const float*)d_in[21];
  const float* ffn_b1  = (const float*)d_in[22];
  const float* ffn_w2  = (const float*)d_in[23];
  const float* ffn_b2  = (const float*)d_in[24];
  const float* head_w  = (const float*)d_in[25];
  const float* head_b  = (const float*)d_in[26];

  float *mv_il, *mv_hl;

  if (ws_size >= needMFMA) {
    // ================= MFMA path =================
    char* base = (char*)d_ws;
    bf16* msgA = (bf16*)base;
    bf16* msgB = (bf16*)(base + msgBytes);
    bf16* nei  = (bf16*)(base + 2 * msgBytes);
    bf16* WiT  = (bf16*)(base + 2 * msgBytes + neiBytes);
    bf16* WhT  = WiT + 320 * 160;
    bf16* WoT  = WhT + 320 * 320;
    float* mvf = (float*)(base + 2 * msgBytes + neiBytes + wtBytes);
    mv_il = mvf; mv_hl = mvf + nMol;
    bf16* fa16 = msgB;
    bf16* fb16 = msgB + (size_t)N_ATOMS * 144;
    float* atom_h = (float*)msgA;

    const dim3 gB((N_BONDS + 127) / 128, 5);
    const dim3 gA((N_ATOMS + 127) / 128, 5);
    const int neiBlk = (N_ATOMS * 40 + 255) / 256;
    const int nmBlk  = (N_BONDS * 40 + 255) / 256;

    for (int c = 0; c < 2; ++c) {
      const float* fa      = (const float*)d_in[c * 10 + 0];
      const float* fb      = (const float*)d_in[c * 10 + 1];
      const int*   a2b     = (const int*)d_in[c * 10 + 2];
      const int*   b2a     = (const int*)d_in[c * 10 + 3];
      const int*   b2revb  = (const int*)d_in[c * 10 + 4];
      const int*   mol_ids = (const int*)d_in[c * 10 + 5];
      const float* W_i     = (const float*)d_in[c * 10 + 6];
      const float* W_h     = (const float*)d_in[c * 10 + 7];
      const float* W_o_w   = (const float*)d_in[c * 10 + 8];
      const float* W_o_b   = (const float*)d_in[c * 10 + 9];
      float* mv = (c == 0) ? mv_il : mv_hl;

      cvt_pad_kernel<<<(N_ATOMS * 144 + 255) / 256, blk, 0, stream>>>(fa, fa16, N_ATOMS, 133, 144);
      cvt_pad_kernel<<<(N_BONDS * 16 + 255) / 256, blk, 0, stream>>>(fb, fb16, N_BONDS, 14, 16);
      wt_fill_kernel<<<(320 * 160 + 255) / 256, blk, 0, stream>>>(W_i, WiT, 300, 160, 133, 144, 133, 14);
      wt_fill_kernel<<<(320 * 320 + 255) / 256, blk, 0, stream>>>(W_h, WhT, 300, 320, 300, 0, 0, 0);
      wt_fill_kernel<<<(320 * 480 + 255) / 256, blk, 0, stream>>>(W_o_w, WoT, 300, 480, 133, 144, 133, 300);

      // msg0 = relu([fa[b2a] | fb] @ W_i)
      mfma_gemm<1, bf16, 5><<<gB, blk, 0, stream>>>(fa16, fb16, b2a, WiT, nullptr,
                                                    msgA, N_BONDS, 300, 320);
      // 2 message-passing steps: gathers full-row, GEMM A linear + GLD staging
      for (int s = 0; s < 2; ++s) {
        nei_sum16_kernel<<<neiBlk, blk, 0, stream>>>(msgA, a2b, nei);
        nm16_kernel<<<nmBlk, blk, 0, stream>>>(nei, msgA, b2a, b2revb, msgB);
        mfma_gemm<0, bf16, 10><<<gB, blk, 0, stream>>>(msgB, nullptr, nullptr, WhT, nullptr,
                                                       msgA, N_BONDS, 300, 320);
      }
      // rebuild fa16 (msgB clobbered by nm), final gather, atom GEMM
      cvt_pad_kernel<<<(N_ATOMS * 144 + 255) / 256, blk, 0, stream>>>(fa, fa16, N_ATOMS, 133, 144);
      nei_sum16_kernel<<<neiBlk, blk, 0, stream>>>(msgA, a2b, nei);
      mfma_gemm<2, float, 15><<<gA, blk, 0, stream>>>(fa16, nei, nullptr, WoT, W_o_b,
                                                      atom_h, N_ATOMS, 300, 300);
      mol_mean_kernel<<<N_MOLS, 320, 0, stream>>>(atom_h, mol_ids, mv, N_ATOMS);
    }
  } else if (ws_size >= needSmall) {
    // ================= legacy bf16-FMA fallback =================
    bf16* p = (bf16*)d_ws;
    bf16* msgA_b = p;  p += nMsg;
    bf16* nm_b   = p;  p += nMsg;
    bf16* nei_b  = p;  p += nNei;
    float* q = (float*)p;
    mv_il = q; q += nMol;  mv_hl = q;
    float* atom_h = (float*)nm_b;

    for (int c = 0; c < 2; ++c) {
      const float* fa      = (const float*)d_in[c * 10 + 0];
      const float* fb      = (const float*)d_in[c * 10 + 1];
      const int*   a2b     = (const int*)d_in[c * 10 + 2];
      const int*   b2a     = (const int*)d_in[c * 10 + 3];
      const int*   b2revb  = (const int*)d_in[c * 10 + 4];
      const int*   mol_ids = (const int*)d_in[c * 10 + 5];
      const float* W_i     = (const float*)d_in[c * 10 + 6];
      const float* W_h     = (const float*)d_in[c * 10 + 7];
      const float* W_o_w   = (const float*)d_in[c * 10 + 8];
      const float* W_o_b   = (const float*)d_in[c * 10 + 9];
      float* mv = (c == 0) ? mv_il : mv_hl;
      run_encoder<bf16>(fa, fb, a2b, b2a, b2revb, mol_ids, W_i, W_h, W_o_w, W_o_b,
                        msgA_b, nm_b, nei_b, atom_h, mv, stream);
    }
  } else {
    hipMemsetAsync(d_out, 0, (size_t)out_size * sizeof(float), stream);
    return;
  }

  // ================= fused FFN + head =================
  ffn_fused_kernel<<<N_MOLS, 320, 0, stream>>>(mv_il, mv_hl, tab,
                                               ffn_w1, ffn_b1, ffn_w2, ffn_b2,
                                               head_w, head_b, (float*)d_out);
}